// Round 6
// baseline (200.188 us; speedup 1.0000x reference)
//
#include <hip/hip_runtime.h>

#define B_TOTAL 2048
#define CAST    128
#define HDIM    256
#define INDIM   256
#define BM      8
#define GRU_BLOCKS (B_TOTAL / BM)     // 256
#define ROW_F4     (CAST * HDIM / 4)  // 8192 float4 per batch row
#define COPY_BLOCKS 2048
#define N4_TOTAL   ((long)B_TOTAL * CAST * HDIM / 4)   // 16,777,216 float4

typedef float fx4 __attribute__((ext_vector_type(4)));

// ---------------- kernel 1: flat copy + prep ----------------
// blocks [0, COPY_BLOCKS): branch-free grid-window copy state->out_state
//   (normal loads for L3 reuse, NT stores to not pollute L2/L3).
// block COPY_BLOCKS: set rowstop flags from story_stop.
// blocks [COPY_BLOCKS+1, COPY_BLOCKS+1+384): weight transpose into wtI/wtH:
//   wt[((k4*3 + gate)*256 + h)*4 + j] = w[(gate*256 + h)*256 + k4*4 + j]
__global__ __launch_bounds__(256) void k_copyprep(
    const float* __restrict__ state, float* __restrict__ out_state,
    const int* __restrict__ story_stop, int n_stop,
    const float* __restrict__ w_ih, const float* __restrict__ w_hh,
    int* rowstop, float* wtI, float* wtH) {
    const int t = threadIdx.x;
    if (blockIdx.x < COPY_BLOCKS) {
        const long stride = (long)COPY_BLOCKS * 256;
        const long base = (long)blockIdx.x * 256 + t;
        const fx4* __restrict__ src = (const fx4*)state;
        fx4* __restrict__ dst = (fx4*)out_state;
        #pragma unroll
        for (int g = 0; g < 4; ++g) {
            fx4 d[8];
            #pragma unroll
            for (int i = 0; i < 8; ++i)
                d[i] = src[base + (long)(g * 8 + i) * stride];
            #pragma unroll
            for (int i = 0; i < 8; ++i)
                __builtin_nontemporal_store(d[i], &dst[base + (long)(g * 8 + i) * stride]);
        }
    } else if (blockIdx.x == COPY_BLOCKS) {
        if (t < n_stop) rowstop[story_stop[t]] = 1;
    } else {
        int id  = blockIdx.x - (COPY_BLOCKS + 1);  // 0..383
        int mat = id / 192;                        // 0: w_ih, 1: w_hh
        int rem = id % 192;
        int g   = rem / 64;
        int k4  = rem % 64;
        const float* w = mat ? w_hh : w_ih;
        float*      wt = mat ? wtH  : wtI;
        float4 wv = *(const float4*)(w + ((size_t)(g * HDIM + t) * INDIM + k4 * 4));
        *(float4*)(wt + ((size_t)((k4 * 3 + g) * HDIM + t)) * 4) = wv;
    }
}

// ---------------- kernel 2: GRU + stop-row zeroing ----------------
// blocks [0, GRU_BLOCKS): GRU on BM rows each; writes out_sel and scatters
//   into out_state (skipping stop rows). blocks [GRU_BLOCKS, +n_stop): zero
//   one stop row each. Scatter targets & stop rows are disjoint.
__global__ __launch_bounds__(256) void k_gru(
    const float* __restrict__ x, const int* __restrict__ batch_idxs,
    const int* __restrict__ actor_ids, const float* __restrict__ state,
    const float* __restrict__ wtI, const float* __restrict__ wtH,
    const float* __restrict__ b_ih, const float* __restrict__ b_hh,
    const int* __restrict__ rowstop, const int* __restrict__ story_stop,
    int n_stop, float* __restrict__ out_sel, float* __restrict__ out_state) {
    __shared__ float xs[BM][INDIM];
    __shared__ float ss[BM][HDIM];
    const int h = threadIdx.x;

    if (blockIdx.x >= GRU_BLOCKS) {
        int zb = blockIdx.x - GRU_BLOCKS;
        if (zb < n_stop) {
            long base = (long)story_stop[zb] * ROW_F4;
            fx4* __restrict__ dst = (fx4*)out_state + base + h;
            const fx4 z = (fx4)(0.f);
            #pragma unroll
            for (int j = 0; j < ROW_F4 / 256; ++j)
                __builtin_nontemporal_store(z, dst + j * 256);
        }
        return;
    }

    const int b0 = blockIdx.x * BM;
    #pragma unroll
    for (int r = 0; r < BM; ++r) {
        int g  = b0 + r;
        int bi = batch_idxs[g];
        int a  = actor_ids[bi];
        a = a < 0 ? 0 : (a > CAST - 1 ? CAST - 1 : a);
        xs[r][h] = x[(size_t)g * INDIM + h];
        ss[r][h] = state[((size_t)bi * CAST + a) * HDIM + h];
    }
    __syncthreads();

    float air[BM], aiz[BM], ain[BM], ahr[BM], ahz[BM], ahn[BM];
    #pragma unroll
    for (int r = 0; r < BM; ++r) { air[r]=0.f; aiz[r]=0.f; ain[r]=0.f; ahr[r]=0.f; ahz[r]=0.f; ahn[r]=0.f; }

    const float4* __restrict__ wtI4 = (const float4*)wtI;
    const float4* __restrict__ wtH4 = (const float4*)wtH;

    for (int k4 = 0; k4 < INDIM / 4; ++k4) {
        float4 wir = wtI4[(k4 * 3 + 0) * HDIM + h];
        float4 wiz = wtI4[(k4 * 3 + 1) * HDIM + h];
        float4 win = wtI4[(k4 * 3 + 2) * HDIM + h];
        float4 whr = wtH4[(k4 * 3 + 0) * HDIM + h];
        float4 whz = wtH4[(k4 * 3 + 1) * HDIM + h];
        float4 whn = wtH4[(k4 * 3 + 2) * HDIM + h];
        #pragma unroll
        for (int r = 0; r < BM; ++r) {
            float4 xv = *(const float4*)(&xs[r][k4 * 4]);
            float4 sv = *(const float4*)(&ss[r][k4 * 4]);
            air[r] = fmaf(xv.w, wir.w, fmaf(xv.z, wir.z, fmaf(xv.y, wir.y, fmaf(xv.x, wir.x, air[r]))));
            aiz[r] = fmaf(xv.w, wiz.w, fmaf(xv.z, wiz.z, fmaf(xv.y, wiz.y, fmaf(xv.x, wiz.x, aiz[r]))));
            ain[r] = fmaf(xv.w, win.w, fmaf(xv.z, win.z, fmaf(xv.y, win.y, fmaf(xv.x, win.x, ain[r]))));
            ahr[r] = fmaf(sv.w, whr.w, fmaf(sv.z, whr.z, fmaf(sv.y, whr.y, fmaf(sv.x, whr.x, ahr[r]))));
            ahz[r] = fmaf(sv.w, whz.w, fmaf(sv.z, whz.z, fmaf(sv.y, whz.y, fmaf(sv.x, whz.x, ahz[r]))));
            ahn[r] = fmaf(sv.w, whn.w, fmaf(sv.z, whn.z, fmaf(sv.y, whn.y, fmaf(sv.x, whn.x, ahn[r]))));
        }
    }

    const float bir = b_ih[h], biz = b_ih[HDIM + h], bin = b_ih[2 * HDIM + h];
    const float bhr = b_hh[h], bhz = b_hh[HDIM + h], bhn = b_hh[2 * HDIM + h];

    #pragma unroll
    for (int r = 0; r < BM; ++r) {
        int g  = b0 + r;
        int bi = batch_idxs[g];
        int a  = actor_ids[bi];
        a = a < 0 ? 0 : (a > CAST - 1 ? CAST - 1 : a);
        float ir = air[r] + bir, iz = aiz[r] + biz, inn = ain[r] + bin;
        float hr = ahr[r] + bhr, hz = ahz[r] + bhz, hn = ahn[r] + bhn;
        float rr = 1.f / (1.f + __expf(-(ir + hr)));
        float zz = 1.f / (1.f + __expf(-(iz + hz)));
        float nn = tanhf(inn + rr * hn);
        float val = (1.f - zz) * nn + zz * ss[r][h];
        out_sel[(size_t)g * HDIM + h] = val;
        if (!rowstop[bi]) out_state[((size_t)bi * CAST + a) * HDIM + h] = val;
    }
}

extern "C" void kernel_launch(void* const* d_in, const int* in_sizes, int n_in,
                              void* d_out, int out_size, void* d_ws, size_t ws_size,
                              hipStream_t stream) {
    const float* x          = (const float*)d_in[0];
    const int*   batch_idxs = (const int*)d_in[1];
    const int*   actor_ids  = (const int*)d_in[2];
    const int*   story_stop = (const int*)d_in[3];
    const float* state      = (const float*)d_in[4];
    const float* w_ih       = (const float*)d_in[5];
    const float* w_hh       = (const float*)d_in[6];
    const float* b_ih       = (const float*)d_in[7];
    const float* b_hh       = (const float*)d_in[8];
    const int    n_stop     = in_sizes[3];

    float* out_sel   = (float*)d_out;
    float* out_state = out_sel + (size_t)B_TOTAL * HDIM;

    int*   rowstop = (int*)d_ws;
    float* wtI     = (float*)((char*)d_ws + 16384);
    float* wtH     = wtI + (size_t)3 * HDIM * INDIM;

    hipMemsetAsync(rowstop, 0, B_TOTAL * sizeof(int), stream);
    k_copyprep<<<COPY_BLOCKS + 1 + 384, 256, 0, stream>>>(
        state, out_state, story_stop, n_stop, w_ih, w_hh, rowstop, wtI, wtH);
    k_gru<<<GRU_BLOCKS + 128, 256, 0, stream>>>(
        x, batch_idxs, actor_ids, state, wtI, wtH, b_ih, b_hh,
        rowstop, story_stop, n_stop, out_sel, out_state);
}